// Round 11
// baseline (324.781 us; speedup 1.0000x reference)
//
#include <hip/hip_runtime.h>

// emb-lookup -> LSTM(64) over T=512 -> Dense(3) -> softmax.
// R9-R11 RESTRUCTURE: ONE WAVE (64 thr) PER SEQUENCE. 512 blocks x 64 thr.
// Lane u owns hidden unit u: all 4 gate cols (u, u+64g), fp16 weight pairs in
// 128 VGPRs (waves_per_eu(1,1) -> 512-reg budget, grid is 2 waves/CU anyway).
// Per step: h broadcast IN-REGISTER (ds_swizzle xor1 + cvt_pkrtz + 32 readlane
// -> SGPR half2 pairs consumed by v_dot2_f32_f16, 1-SGPR/instr rule OK).
// Gate math fully lane-local. NO __syncthreads, NO LDS in the recurrence.
// Rationale: R7->R8 halved real math but wall only -6% -- the 4-wave design's
// per-step h write->barrier->read round-trip + wave skew was the floor.
// x-proj (+bias) precomputed as table[VOCAB][256] in d_ws, prefetched 2 ahead.
// R11 fix vs R10: cvt_pkrtz returns __fp16x2, not _Float16x2 -- bit-cast its
// result directly to int. (R10 fix: if constexpr for dead-branch arrays.)
// (R5: v_pk_fma_f32 can't encode AGPR srcs. R6: lgkm-only barrier neutral.
//  R8: fp16 weights absmax 1.95e-3 << 6.9e-3 threshold.)

#define VOCAB 50000
#define EMB 32
#define HID 64
#define NCLS 3
#define BATCH 512
#define TSEQ 512
#define FOURH 256
#define LOG2E 1.4426950408889634f

typedef _Float16 v2h __attribute__((ext_vector_type(2)));

__device__ __forceinline__ v2h bch(int i) { return __builtin_bit_cast(v2h, i); }

#define PIN8(A, o) asm volatile("" : "+v"(A[o]), "+v"(A[o+1]), "+v"(A[o+2]), "+v"(A[o+3]), \
                                     "+v"(A[o+4]), "+v"(A[o+5]), "+v"(A[o+6]), "+v"(A[o+7]))

__device__ __forceinline__ float sigf(float z) {   // 1/(1+2^(-z*log2e))
    return __builtin_amdgcn_rcpf(1.0f + __builtin_amdgcn_exp2f(-LOG2E * z));
}
__device__ __forceinline__ float tanhf_fast(float z) {  // 2*sig(2z)-1
    return fmaf(2.0f, __builtin_amdgcn_rcpf(1.0f + __builtin_amdgcn_exp2f(-2.0f * LOG2E * z)), -1.0f);
}

// table[v][c] = emb[v,:] @ Wk[:,c] + bias[c]
__global__ __launch_bounds__(256)
void build_table_kernel(const float* __restrict__ emb, const float* __restrict__ Wk,
                        const float* __restrict__ bias, float* __restrict__ table) {
    const int c = threadIdx.x;
    const float bb = bias[c];
    float wcol[EMB];
#pragma unroll
    for (int k = 0; k < EMB; ++k) wcol[k] = Wk[k * FOURH + c];
    for (int v = blockIdx.x; v < VOCAB; v += gridDim.x) {
        const float4* er = (const float4*)(emb + (long)v * EMB);
        float acc = bb;
#pragma unroll
        for (int kk = 0; kk < EMB / 4; ++kk) {
            const float4 e = er[kk];
            acc = fmaf(e.x, wcol[kk * 4 + 0], acc);
            acc = fmaf(e.y, wcol[kk * 4 + 1], acc);
            acc = fmaf(e.z, wcol[kk * 4 + 2], acc);
            acc = fmaf(e.w, wcol[kk * 4 + 3], acc);
        }
        table[(long)v * FOURH + c] = acc;
    }
}

template <bool USE_TABLE>
__global__ __launch_bounds__(64) __attribute__((amdgpu_waves_per_eu(1, 1)))
void lstm_kernel(const int* __restrict__ tokens, const float* __restrict__ emb,
                 const float* __restrict__ Wk, const float* __restrict__ Wr,
                 const float* __restrict__ bias, const float* __restrict__ Wd,
                 const float* __restrict__ bd, const float* __restrict__ table,
                 float* __restrict__ out)
{
    const int u   = threadIdx.x;        // hidden unit 0..63
    const int seq = blockIdx.x;
    const long tokbase = (long)seq * TSEQ;

    // recurrent weights: 4 gate cols x 32 k-pairs -> 128 half2 (int-packed)
    int wrh[4][32];
#pragma unroll
    for (int g = 0; g < 4; ++g) {
        const int cc = u + (g << 6);
#pragma unroll
        for (int m = 0; m < 32; ++m) {
            v2h t;
            t.x = (_Float16)Wr[(2 * m) * FOURH + cc];
            t.y = (_Float16)Wr[(2 * m + 1) * FOURH + cc];
            wrh[g][m] = __builtin_bit_cast(int, t);
        }
    }

    int wkh[4][16];      // fallback x-weights fp16 (only touched if !USE_TABLE)
    float bmine[4];
    if constexpr (!USE_TABLE) {
#pragma unroll
        for (int g = 0; g < 4; ++g) {
            const int cc = u + (g << 6);
            bmine[g] = bias[cc];
#pragma unroll
            for (int m = 0; m < 16; ++m) {
                v2h t;
                t.x = (_Float16)Wk[(2 * m) * FOURH + cc];
                t.y = (_Float16)Wk[(2 * m + 1) * FOURH + cc];
                wkh[g][m] = __builtin_bit_cast(int, t);
            }
        }
    }

    float zxA[4], zxB[4], zxC[4];
    if constexpr (USE_TABLE) {
        const int t0 = tokens[tokbase], t1 = tokens[tokbase + 1];
#pragma unroll
        for (int g = 0; g < 4; ++g) {
            zxA[g] = table[(long)t0 * FOURH + u + (g << 6)];
            zxB[g] = table[(long)t1 * FOURH + u + (g << 6)];
        }
    }

    float c = 0.0f, h = 0.0f;

    for (int t = 0; t < TSEQ; ++t) {
        PIN8(wrh[0], 0); PIN8(wrh[0], 8); PIN8(wrh[0], 16); PIN8(wrh[0], 24);
        PIN8(wrh[1], 0); PIN8(wrh[1], 8); PIN8(wrh[1], 16); PIN8(wrh[1], 24);
        PIN8(wrh[2], 0); PIN8(wrh[2], 8); PIN8(wrh[2], 16); PIN8(wrh[2], 24);
        PIN8(wrh[3], 0); PIN8(wrh[3], 8); PIN8(wrh[3], 16); PIN8(wrh[3], 24);

        // prefetch zx(t+2)
        if constexpr (USE_TABLE) {
            const int tn  = (t + 2 < TSEQ) ? t + 2 : TSEQ - 1;
            const int tok = tokens[tokbase + tn];
#pragma unroll
            for (int g = 0; g < 4; ++g)
                zxC[g] = table[(long)tok * FOURH + u + (g << 6)];
        }

        // in-register h broadcast: pack (h[2m], h[2m+1]) on even lanes, readlane
        const float other = __builtin_bit_cast(float,
            __builtin_amdgcn_ds_swizzle(__builtin_bit_cast(int, h), 0x041F)); // lane^1
        const int pki = __builtin_bit_cast(int, __builtin_amdgcn_cvt_pkrtz(h, other));
        int hs[32];
#pragma unroll
        for (int m = 0; m < 32; ++m) hs[m] = __builtin_amdgcn_readlane(pki, 2 * m);

        float p0, p1, p2, p3;
        if constexpr (USE_TABLE) { p0 = zxA[0]; p1 = zxA[1]; p2 = zxA[2]; p3 = zxA[3]; }
        else                     { p0 = bmine[0]; p1 = bmine[1]; p2 = bmine[2]; p3 = bmine[3]; }

#pragma unroll
        for (int m = 0; m < 32; ++m) {
            const v2h hm = bch(hs[m]);
            p0 = __builtin_amdgcn_fdot2(bch(wrh[0][m]), hm, p0, false);
            p1 = __builtin_amdgcn_fdot2(bch(wrh[1][m]), hm, p1, false);
            p2 = __builtin_amdgcn_fdot2(bch(wrh[2][m]), hm, p2, false);
            p3 = __builtin_amdgcn_fdot2(bch(wrh[3][m]), hm, p3, false);
        }

        if constexpr (!USE_TABLE) {
            // x-contribution: emb row is wave-uniform -> scalar loads
            const int tok = tokens[tokbase + t];
            const float* er = emb + (long)tok * EMB;
#pragma unroll
            for (int m = 0; m < 16; ++m) {
                v2h xm;
                xm.x = (_Float16)er[2 * m];
                xm.y = (_Float16)er[2 * m + 1];
                p0 = __builtin_amdgcn_fdot2(bch(wkh[0][m]), xm, p0, false);
                p1 = __builtin_amdgcn_fdot2(bch(wkh[1][m]), xm, p1, false);
                p2 = __builtin_amdgcn_fdot2(bch(wkh[2][m]), xm, p2, false);
                p3 = __builtin_amdgcn_fdot2(bch(wkh[3][m]), xm, p3, false);
            }
        }

        const float gi = sigf(p0);
        const float gf = sigf(p1);
        const float gg = tanhf_fast(p2);
        const float go = sigf(p3);

        c = fmaf(gf, c, gi * gg);
        h = go * tanhf_fast(c);

        if constexpr (USE_TABLE) {
#pragma unroll
            for (int g = 0; g < 4; ++g) { zxA[g] = zxB[g]; zxB[g] = zxC[g]; }
        }
    }

    // Dense(3) + softmax: wave-wide butterfly reduction of h*Wd columns
    float pw0 = h * Wd[u * NCLS + 0];
    float pw1 = h * Wd[u * NCLS + 1];
    float pw2 = h * Wd[u * NCLS + 2];
#pragma unroll
    for (int k = 32; k >= 1; k >>= 1) {
        pw0 += __shfl_xor(pw0, k, 64);
        pw1 += __shfl_xor(pw1, k, 64);
        pw2 += __shfl_xor(pw2, k, 64);
    }
    if (u == 0) {
        const float l0 = pw0 + bd[0], l1 = pw1 + bd[1], l2 = pw2 + bd[2];
        const float mm = fmaxf(l0, fmaxf(l1, l2));
        const float e0 = __builtin_amdgcn_exp2f((l0 - mm) * LOG2E);
        const float e1 = __builtin_amdgcn_exp2f((l1 - mm) * LOG2E);
        const float e2 = __builtin_amdgcn_exp2f((l2 - mm) * LOG2E);
        const float inv = __builtin_amdgcn_rcpf(e0 + e1 + e2);
        out[seq * NCLS + 0] = e0 * inv;
        out[seq * NCLS + 1] = e1 * inv;
        out[seq * NCLS + 2] = e2 * inv;
    }
}

extern "C" void kernel_launch(void* const* d_in, const int* in_sizes, int n_in,
                              void* d_out, int out_size, void* d_ws, size_t ws_size,
                              hipStream_t stream) {
    const int*   tokens = (const int*)  d_in[0];
    const float* emb    = (const float*)d_in[1];
    const float* Wk     = (const float*)d_in[2];
    const float* Wr     = (const float*)d_in[3];
    const float* b      = (const float*)d_in[4];
    const float* Wd     = (const float*)d_in[5];
    const float* bd     = (const float*)d_in[6];
    float* out = (float*)d_out;

    const size_t need = (size_t)VOCAB * FOURH * sizeof(float);
    if (ws_size >= need) {
        float* table = (float*)d_ws;
        build_table_kernel<<<dim3(2048), dim3(256), 0, stream>>>(emb, Wk, b, table);
        lstm_kernel<true><<<dim3(BATCH), dim3(64), 0, stream>>>(
            tokens, emb, Wk, Wr, b, Wd, bd, table, out);
    } else {
        lstm_kernel<false><<<dim3(BATCH), dim3(64), 0, stream>>>(
            tokens, emb, Wk, Wr, b, Wd, bd, nullptr, out);
    }
}

// Round 12
// 310.325 us; speedup vs baseline: 1.0466x; 1.0466x over previous
//
#include <hip/hip_runtime.h>

// emb-lookup -> LSTM(64) over T=512 -> Dense(3) -> softmax.
// ONE WAVE (64 thr) PER SEQUENCE; 512 blocks x 64 thr. Lane u owns unit u
// (4 gate cols u+64g), fp16 weight pairs in 128 pinned VGPRs.
// R12: h broadcast via WAVE-LOCAL LDS (no barrier: single wave, DS queue is
// in-order): lane u ds_write_b16 fp16 h at step end; next step 8 broadcast
// ds_read_b128 -> 32 VGPR half2 pairs -> v_dot2_f32_f16 all-VGPR.
// Rationale: R11's readlane broadcast cost ~600 cyc/step in VALU<->SALU
// pipeline hazards (32x v_readlane + swizzle); per-step wall 1200 cyc vs
// ~520 modeled. Serial recurrence => total = 512 x critical path; only
// chain cuts matter.  x-proj(+bias) precomputed as table[VOCAB][256] in
// d_ws, prefetched 2 steps ahead.
// (R5: v_pk_fma_f32 can't read AGPRs. R6: lgkm-only barrier neutral.
//  R8: fp16 weights absmax 1.95e-3 << 6.9e-3. R11: VGPR132 = pins work.)

#define VOCAB 50000
#define EMB 32
#define HID 64
#define NCLS 3
#define BATCH 512
#define TSEQ 512
#define FOURH 256
#define LOG2E 1.4426950408889634f

typedef _Float16 v2h __attribute__((ext_vector_type(2)));

__device__ __forceinline__ v2h bch(int i) { return __builtin_bit_cast(v2h, i); }

#define PIN8(A, o) asm volatile("" : "+v"(A[o]), "+v"(A[o+1]), "+v"(A[o+2]), "+v"(A[o+3]), \
                                     "+v"(A[o+4]), "+v"(A[o+5]), "+v"(A[o+6]), "+v"(A[o+7]))

__device__ __forceinline__ float sigf(float z) {   // 1/(1+2^(-z*log2e))
    return __builtin_amdgcn_rcpf(1.0f + __builtin_amdgcn_exp2f(-LOG2E * z));
}
__device__ __forceinline__ float tanhf_fast(float z) {  // 2*sig(2z)-1
    return fmaf(2.0f, __builtin_amdgcn_rcpf(1.0f + __builtin_amdgcn_exp2f(-2.0f * LOG2E * z)), -1.0f);
}

// table[v][c] = emb[v,:] @ Wk[:,c] + bias[c]
__global__ __launch_bounds__(256)
void build_table_kernel(const float* __restrict__ emb, const float* __restrict__ Wk,
                        const float* __restrict__ bias, float* __restrict__ table) {
    const int c = threadIdx.x;
    const float bb = bias[c];
    float wcol[EMB];
#pragma unroll
    for (int k = 0; k < EMB; ++k) wcol[k] = Wk[k * FOURH + c];
    for (int v = blockIdx.x; v < VOCAB; v += gridDim.x) {
        const float4* er = (const float4*)(emb + (long)v * EMB);
        float acc = bb;
#pragma unroll
        for (int kk = 0; kk < EMB / 4; ++kk) {
            const float4 e = er[kk];
            acc = fmaf(e.x, wcol[kk * 4 + 0], acc);
            acc = fmaf(e.y, wcol[kk * 4 + 1], acc);
            acc = fmaf(e.z, wcol[kk * 4 + 2], acc);
            acc = fmaf(e.w, wcol[kk * 4 + 3], acc);
        }
        table[(long)v * FOURH + c] = acc;
    }
}

template <bool USE_TABLE>
__global__ __launch_bounds__(64) __attribute__((amdgpu_waves_per_eu(1, 1)))
void lstm_kernel(const int* __restrict__ tokens, const float* __restrict__ emb,
                 const float* __restrict__ Wk, const float* __restrict__ Wr,
                 const float* __restrict__ bias, const float* __restrict__ Wd,
                 const float* __restrict__ bd, const float* __restrict__ table,
                 float* __restrict__ out)
{
    __shared__ __align__(16) int hlds[HID / 2];   // 64 fp16 = 128 B

    const int u   = threadIdx.x;        // hidden unit 0..63
    const int seq = blockIdx.x;
    const long tokbase = (long)seq * TSEQ;

    // recurrent weights: 4 gate cols x 32 k-pairs -> 128 half2 (int-packed)
    int wrh[4][32];
#pragma unroll
    for (int g = 0; g < 4; ++g) {
        const int cc = u + (g << 6);
#pragma unroll
        for (int m = 0; m < 32; ++m) {
            v2h t;
            t.x = (_Float16)Wr[(2 * m) * FOURH + cc];
            t.y = (_Float16)Wr[(2 * m + 1) * FOURH + cc];
            wrh[g][m] = __builtin_bit_cast(int, t);
        }
    }

    int wkh[4][16];      // fallback x-weights fp16 (only touched if !USE_TABLE)
    float bmine[4];
    if constexpr (!USE_TABLE) {
#pragma unroll
        for (int g = 0; g < 4; ++g) {
            const int cc = u + (g << 6);
            bmine[g] = bias[cc];
#pragma unroll
            for (int m = 0; m < 16; ++m) {
                v2h t;
                t.x = (_Float16)Wk[(2 * m) * FOURH + cc];
                t.y = (_Float16)Wk[(2 * m + 1) * FOURH + cc];
                wkh[g][m] = __builtin_bit_cast(int, t);
            }
        }
    }

    float zxA[4], zxB[4], zxC[4];
    if constexpr (USE_TABLE) {
        const int t0 = tokens[tokbase], t1 = tokens[tokbase + 1];
#pragma unroll
        for (int g = 0; g < 4; ++g) {
            zxA[g] = table[(long)t0 * FOURH + u + (g << 6)];
            zxB[g] = table[(long)t1 * FOURH + u + (g << 6)];
        }
    }

    // h(0) = 0 into LDS (single wave: in-order DS queue, no barrier needed)
    ((_Float16*)hlds)[u] = (_Float16)0.0f;

    float c = 0.0f, h = 0.0f;

    for (int t = 0; t < TSEQ; ++t) {
        PIN8(wrh[0], 0); PIN8(wrh[0], 8); PIN8(wrh[0], 16); PIN8(wrh[0], 24);
        PIN8(wrh[1], 0); PIN8(wrh[1], 8); PIN8(wrh[1], 16); PIN8(wrh[1], 24);
        PIN8(wrh[2], 0); PIN8(wrh[2], 8); PIN8(wrh[2], 16); PIN8(wrh[2], 24);
        PIN8(wrh[3], 0); PIN8(wrh[3], 8); PIN8(wrh[3], 16); PIN8(wrh[3], 24);

        // prefetch zx(t+2)
        if constexpr (USE_TABLE) {
            const int tn  = (t + 2 < TSEQ) ? t + 2 : TSEQ - 1;
            const int tok = tokens[tokbase + tn];
#pragma unroll
            for (int g = 0; g < 4; ++g)
                zxC[g] = table[(long)tok * FOURH + u + (g << 6)];
        }

        // broadcast h: 8 x ds_read_b128 (same addr all lanes = broadcast)
        int hp[32];
#pragma unroll
        for (int m = 0; m < 8; ++m) {
            const int4 r = ((const int4*)hlds)[m];
            hp[4 * m + 0] = r.x; hp[4 * m + 1] = r.y;
            hp[4 * m + 2] = r.z; hp[4 * m + 3] = r.w;
        }

        float p0, p1, p2, p3;
        if constexpr (USE_TABLE) { p0 = zxA[0]; p1 = zxA[1]; p2 = zxA[2]; p3 = zxA[3]; }
        else                     { p0 = bmine[0]; p1 = bmine[1]; p2 = bmine[2]; p3 = bmine[3]; }

#pragma unroll
        for (int m = 0; m < 32; ++m) {
            const v2h hm = bch(hp[m]);
            p0 = __builtin_amdgcn_fdot2(bch(wrh[0][m]), hm, p0, false);
            p1 = __builtin_amdgcn_fdot2(bch(wrh[1][m]), hm, p1, false);
            p2 = __builtin_amdgcn_fdot2(bch(wrh[2][m]), hm, p2, false);
            p3 = __builtin_amdgcn_fdot2(bch(wrh[3][m]), hm, p3, false);
        }

        if constexpr (!USE_TABLE) {
            // x-contribution: emb row is wave-uniform -> scalar loads
            const int tok = tokens[tokbase + t];
            const float* er = emb + (long)tok * EMB;
#pragma unroll
            for (int m = 0; m < 16; ++m) {
                v2h xm;
                xm.x = (_Float16)er[2 * m];
                xm.y = (_Float16)er[2 * m + 1];
                p0 = __builtin_amdgcn_fdot2(bch(wkh[0][m]), xm, p0, false);
                p1 = __builtin_amdgcn_fdot2(bch(wkh[1][m]), xm, p1, false);
                p2 = __builtin_amdgcn_fdot2(bch(wkh[2][m]), xm, p2, false);
                p3 = __builtin_amdgcn_fdot2(bch(wkh[3][m]), xm, p3, false);
            }
        }

        const float gi = sigf(p0);
        const float gf = sigf(p1);
        const float gg = tanhf_fast(p2);
        const float go = sigf(p3);

        c = fmaf(gf, c, gi * gg);
        h = go * tanhf_fast(c);

        // publish h(t+1) for next step (in-order DS: reads above already done)
        ((_Float16*)hlds)[u] = (_Float16)h;

        if constexpr (USE_TABLE) {
#pragma unroll
            for (int g = 0; g < 4; ++g) { zxA[g] = zxB[g]; zxB[g] = zxC[g]; }
        }
    }

    // Dense(3) + softmax: wave-wide butterfly reduction of h*Wd columns
    float pw0 = h * Wd[u * NCLS + 0];
    float pw1 = h * Wd[u * NCLS + 1];
    float pw2 = h * Wd[u * NCLS + 2];
#pragma unroll
    for (int k = 32; k >= 1; k >>= 1) {
        pw0 += __shfl_xor(pw0, k, 64);
        pw1 += __shfl_xor(pw1, k, 64);
        pw2 += __shfl_xor(pw2, k, 64);
    }
    if (u == 0) {
        const float l0 = pw0 + bd[0], l1 = pw1 + bd[1], l2 = pw2 + bd[2];
        const float mm = fmaxf(l0, fmaxf(l1, l2));
        const float e0 = __builtin_amdgcn_exp2f((l0 - mm) * LOG2E);
        const float e1 = __builtin_amdgcn_exp2f((l1 - mm) * LOG2E);
        const float e2 = __builtin_amdgcn_exp2f((l2 - mm) * LOG2E);
        const float inv = __builtin_amdgcn_rcpf(e0 + e1 + e2);
        out[seq * NCLS + 0] = e0 * inv;
        out[seq * NCLS + 1] = e1 * inv;
        out[seq * NCLS + 2] = e2 * inv;
    }
}

extern "C" void kernel_launch(void* const* d_in, const int* in_sizes, int n_in,
                              void* d_out, int out_size, void* d_ws, size_t ws_size,
                              hipStream_t stream) {
    const int*   tokens = (const int*)  d_in[0];
    const float* emb    = (const float*)d_in[1];
    const float* Wk     = (const float*)d_in[2];
    const float* Wr     = (const float*)d_in[3];
    const float* b      = (const float*)d_in[4];
    const float* Wd     = (const float*)d_in[5];
    const float* bd     = (const float*)d_in[6];
    float* out = (float*)d_out;

    const size_t need = (size_t)VOCAB * FOURH * sizeof(float);
    if (ws_size >= need) {
        float* table = (float*)d_ws;
        build_table_kernel<<<dim3(2048), dim3(256), 0, stream>>>(emb, Wk, b, table);
        lstm_kernel<true><<<dim3(BATCH), dim3(64), 0, stream>>>(
            tokens, emb, Wk, Wr, b, Wd, bd, table, out);
    } else {
        lstm_kernel<false><<<dim3(BATCH), dim3(64), 0, stream>>>(
            tokens, emb, Wk, Wr, b, Wd, bd, nullptr, out);
    }
}